// Round 3
// baseline (744.761 us; speedup 1.0000x reference)
//
#include <hip/hip_runtime.h>

// S=2048, B=32, H=1024
// out[b][s] = softmax_s( sum_n tanh( (Enc @ We^T)[m][n] + pre_h[b][n] + bias[n] ) * v[n] ),  m = s*32+b

#define LDT 40   // As row stride in shorts: 80 B = 5*16 B (aligned b128), ~2-way banks

typedef __attribute__((ext_vector_type(8))) short short8;
typedef __attribute__((ext_vector_type(4))) float floatx4;
typedef __attribute__((ext_vector_type(4))) unsigned int uint4v;

#define GLDS(g, l) __builtin_amdgcn_global_load_lds( \
    (const __attribute__((address_space(1))) void*)(g), \
    (__attribute__((address_space(3))) void*)(l), 16, 0, 0)

__device__ __forceinline__ unsigned short f2b(float f) {   // RNE
  union { float f; unsigned u; } c; c.f = f;
  unsigned r = c.u + 0x7fffu + ((c.u >> 16) & 1u);
  return (unsigned short)(r >> 16);
}

// round-to-nearest both floats, pack bf16(hi)<<16 | bf16(lo) in ONE v_perm
__device__ __forceinline__ unsigned pack2(float lo, float hi) {
  union { float f; unsigned u; } a, b; a.f = lo; b.f = hi;
  return __builtin_amdgcn_perm(b.u + 0x8000u, a.u + 0x8000u, 0x07060302u);
}

__device__ __forceinline__ float fast_tanh(float x) {
  float e = __expf(2.0f * x);
  return 1.0f - 2.0f / (e + 1.0f);
}

// We (fp32, W[:,1024:2048]) -> bf16 [1024][1024] in ws; also zeroes scoresT.
__global__ __launch_bounds__(256) void k_cvtB(
    const float* __restrict__ W, unsigned int* __restrict__ Bw,
    float* __restrict__ scoresT) {
  const int idx = blockIdx.x * 256 + threadIdx.x;    // 0..262143, 4 elems each
  const int row = idx >> 8, col = (idx & 255) << 2;
  float4 f = *(const float4*)(W + (size_t)row * 2048 + 1024 + col);
  unsigned u0 = (unsigned)f2b(f.x) | ((unsigned)f2b(f.y) << 16);
  unsigned u1 = (unsigned)f2b(f.z) | ((unsigned)f2b(f.w) << 16);
  uint2 u = {u0, u1};
  *(uint2*)(Bw + ((size_t)row * 1024 + col) / 2) = u;
  if (blockIdx.x < 256) scoresT[blockIdx.x * 256 + threadIdx.x] = 0.f;
}

// tpre[b][k] = sum_j hidden[b][j]*W[k][j] + bias[k]  (one wave per (b,k))
__global__ __launch_bounds__(256) void k_preh(
    const float* __restrict__ hidden, const float* __restrict__ W,
    const float* __restrict__ bias, float* __restrict__ tpre) {
  const int wv   = (blockIdx.x << 2) + (threadIdx.x >> 6);
  const int lane = threadIdx.x & 63;
  const int b = wv & 31;
  const int k = wv >> 5;
  const float* wr = W + (size_t)k * 2048;
  const float* hr = hidden + b * 1024;
  float s = 0.f;
  #pragma unroll
  for (int j = 0; j < 1024; j += 64) s += wr[j + lane] * hr[j + lane];
  #pragma unroll
  for (int off = 32; off; off >>= 1) s += __shfl_xor(s, off, 64);
  if (lane == 0) tpre[b * 1024 + k] = s + bias[k];
}

// Fused GEMM + tanh + v-dot. 128x128 tile, BK=32, 4 waves, DOUBLE-BUFFERED
// LDS with ONE barrier per K-iteration: loads for k+1 issued before the
// MFMAs of k, so HBM/L2 latency is covered by compute.
__global__ __launch_bounds__(256) void k_gemm(
    const float* __restrict__ A,              // enc [65536][1024] fp32
    const unsigned short* __restrict__ Bw,    // We bf16 [1024][1024]
    const float* __restrict__ tpre,           // [32][1024]
    const float* __restrict__ vvec,           // [1024]
    float* __restrict__ scoresT) {            // [32][2048], pre-zeroed
  __shared__ short As[2][128 * LDT];
  __shared__ short Bs[2][128 * 32];

  // XCD swizzle: 8 n-tiles of one m-panel at same blockIdx%8 -> same XCD L2
  const int l = blockIdx.x;
  const int x = l & 7, j = l >> 3;
  const int Mbase = (x * 64 + (j >> 3)) * 128;
  const int Nbase = (j & 7) * 128;

  const int tid = threadIdx.x, lane = tid & 63, w = tid >> 6;
  const int wm = w >> 1, wn = w & 1;
  const int c = lane & 15, q = lane >> 4;

  // A staging: thread -> row tid>>1, 16 consecutive k at (tid&1)*16
  const int aoff = (tid >> 1) * LDT + ((tid & 1) << 4);
  const float* ap = A + (size_t)(Mbase + (tid >> 1)) * 1024 + ((tid & 1) << 4);

  // B staging: wave w covers rows [w*32, w*32+32), 2 glds instrs of 16 rows
  const unsigned short* bg0 =
      Bw + (size_t)(Nbase + w * 32 + (lane >> 2)) * 1024 + ((lane & 3) << 3);
  const unsigned short* bg1 = bg0 + (size_t)16 * 1024;
  const int boff0 = (w * 32) * 32;
  const int boff1 = (w * 32 + 16) * 32;

  floatx4 acc[4][4];
  #pragma unroll
  for (int mt = 0; mt < 4; ++mt)
    #pragma unroll
    for (int nt = 0; nt < 4; ++nt) {
      floatx4 z = {0.f, 0.f, 0.f, 0.f};
      acc[mt][nt] = z;
    }

  // ---- prologue: stage k-chunk 0 into buffer 0 ----
  {
    float4 f0 = *(const float4*)(ap);
    float4 f1 = *(const float4*)(ap + 4);
    float4 f2 = *(const float4*)(ap + 8);
    float4 f3 = *(const float4*)(ap + 12);
    GLDS(bg0, &Bs[0][boff0]);
    GLDS(bg1, &Bs[0][boff1]);
    uint4v u0 = {pack2(f0.x, f0.y), pack2(f0.z, f0.w),
                 pack2(f1.x, f1.y), pack2(f1.z, f1.w)};
    uint4v u1 = {pack2(f2.x, f2.y), pack2(f2.z, f2.w),
                 pack2(f3.x, f3.y), pack2(f3.z, f3.w)};
    *(uint4v*)&As[0][aoff] = u0;
    *(uint4v*)&As[0][aoff + 8] = u1;
  }
  __syncthreads();

  for (int k0 = 0; k0 < 1024; k0 += 32) {
    const int cur = (k0 >> 5) & 1;
    const int nxt = cur ^ 1;
    const bool more = (k0 + 32) < 1024;

    // issue next chunk's loads FIRST (latency overlapped with MFMAs below)
    float4 g0, g1, g2, g3;
    if (more) {
      g0 = *(const float4*)(ap + k0 + 32);
      g1 = *(const float4*)(ap + k0 + 36);
      g2 = *(const float4*)(ap + k0 + 40);
      g3 = *(const float4*)(ap + k0 + 44);
      GLDS(bg0 + k0 + 32, &Bs[nxt][boff0]);
      GLDS(bg1 + k0 + 32, &Bs[nxt][boff1]);
    }

    short8 af[4], bf[4];
    #pragma unroll
    for (int mt = 0; mt < 4; ++mt)
      af[mt] = *(const short8*)&As[cur][(wm * 64 + mt * 16 + c) * LDT + q * 8];
    #pragma unroll
    for (int nt = 0; nt < 4; ++nt)
      bf[nt] = *(const short8*)&Bs[cur][(wn * 64 + nt * 16 + c) * 32 + q * 8];
    #pragma unroll
    for (int mt = 0; mt < 4; ++mt)
      #pragma unroll
      for (int nt = 0; nt < 4; ++nt)
        acc[mt][nt] = __builtin_amdgcn_mfma_f32_16x16x32_bf16(
            af[mt], bf[nt], acc[mt][nt], 0, 0, 0);

    if (more) {
      uint4v u0 = {pack2(g0.x, g0.y), pack2(g0.z, g0.w),
                   pack2(g1.x, g1.y), pack2(g1.z, g1.w)};
      uint4v u1 = {pack2(g2.x, g2.y), pack2(g2.z, g2.w),
                   pack2(g3.x, g3.y), pack2(g3.z, g3.w)};
      *(uint4v*)&As[nxt][aoff] = u0;
      *(uint4v*)&As[nxt][aoff + 8] = u1;
    }
    __syncthreads();
  }

  // Epilogue: score[m] += sum_n tanh(pre_e + tpre[b][n]) * v[n]
  // C layout: col = lane&15, row = (lane>>4)*4 + i
  const int mwave = Mbase + wm * 64;
  const int nwave = Nbase + wn * 64;
  float vv[4];
  #pragma unroll
  for (int nt = 0; nt < 4; ++nt) vv[nt] = vvec[nwave + nt * 16 + c];
  #pragma unroll
  for (int mt = 0; mt < 4; ++mt) {
    #pragma unroll
    for (int i = 0; i < 4; ++i) {
      const int mrow = mwave + mt * 16 + q * 4 + i;
      const float* tb = tpre + (mrow & 31) * 1024;
      float ssum = 0.f;
      #pragma unroll
      for (int nt = 0; nt < 4; ++nt) {
        float pre = acc[mt][nt][i] + tb[nwave + nt * 16 + c];
        ssum += fast_tanh(pre) * vv[nt];
      }
      #pragma unroll
      for (int off = 1; off < 16; off <<= 1) ssum += __shfl_xor(ssum, off, 64);
      if (c == 0) atomicAdd(&scoresT[(mrow & 31) * 2048 + (mrow >> 5)], ssum);
    }
  }
}

// softmax over s for each b: scoresT[b][s] -> out[b][s]  (coalesced)
__global__ __launch_bounds__(256) void k_softmax(
    const float* __restrict__ scoresT, float* __restrict__ out) {
  const int b = blockIdx.x;
  const int t = threadIdx.x;
  const int w = t >> 6, lane = t & 63;
  __shared__ float red[4];
  float vals[8];
  float m = -3.0e38f;
  #pragma unroll
  for (int i = 0; i < 8; ++i) {
    vals[i] = scoresT[b * 2048 + t + 256 * i];
    m = fmaxf(m, vals[i]);
  }
  #pragma unroll
  for (int off = 32; off; off >>= 1) m = fmaxf(m, __shfl_xor(m, off, 64));
  if (lane == 0) red[w] = m;
  __syncthreads();
  m = fmaxf(fmaxf(red[0], red[1]), fmaxf(red[2], red[3]));
  __syncthreads();
  float e[8];
  float sum = 0.f;
  #pragma unroll
  for (int i = 0; i < 8; ++i) { e[i] = __expf(vals[i] - m); sum += e[i]; }
  #pragma unroll
  for (int off = 32; off; off >>= 1) sum += __shfl_xor(sum, off, 64);
  if (lane == 0) red[w] = sum;
  __syncthreads();
  sum = red[0] + red[1] + red[2] + red[3];
  const float inv = 1.0f / sum;
  #pragma unroll
  for (int i = 0; i < 8; ++i) out[b * 2048 + t + 256 * i] = e[i] * inv;
}

extern "C" void kernel_launch(void* const* d_in, const int* in_sizes, int n_in,
                              void* d_out, int out_size, void* d_ws, size_t ws_size,
                              hipStream_t stream) {
  const float* hidden = (const float*)d_in[0];   // (1,32,1024)
  const float* enc    = (const float*)d_in[1];   // (2048,32,1024)
  const float* W      = (const float*)d_in[2];   // (1024,2048)
  const float* bias   = (const float*)d_in[3];   // (1024,)
  const float* vvec   = (const float*)d_in[4];   // (1024,)
  float* out = (float*)d_out;                    // (32,1,2048) fp32

  float* scoresT = (float*)d_ws;                          // 65536 fp32
  float* tpre    = scoresT + 65536;                       // 32768 fp32
  unsigned int* Bw = (unsigned int*)(tpre + 32768);       // 1M bf16 = 2 MB

  hipLaunchKernelGGL(k_cvtB, dim3(1024), dim3(256), 0, stream, W, Bw, scoresT);
  hipLaunchKernelGGL(k_preh, dim3(8192), dim3(256), 0, stream, hidden, W, bias, tpre);
  hipLaunchKernelGGL(k_gemm, dim3(4096), dim3(256), 0, stream,
                     enc, (const unsigned short*)Bw, tpre, vvec, scoresT);
  hipLaunchKernelGGL(k_softmax, dim3(32), dim3(256), 0, stream, scoresT, out);
}

// Round 4
// 596.978 us; speedup vs baseline: 1.2476x; 1.2476x over previous
//
#include <hip/hip_runtime.h>

// S=2048, B=32, H=1024
// out[b][s] = softmax_s( sum_n tanh( (Enc @ We^T)[m][n] + pre_h[b][n] + bias[n] ) * v[n] ),  m = s*32+b

#define LDA 72   // As row stride in shorts: 144 B = 9*16B (aligned b128), rows phase-shift 4 banks

typedef __attribute__((ext_vector_type(8))) short short8;
typedef __attribute__((ext_vector_type(4))) float floatx4;
typedef __attribute__((ext_vector_type(4))) unsigned int uint4v;

#define GLDS(g, l) __builtin_amdgcn_global_load_lds( \
    (const __attribute__((address_space(1))) void*)(g), \
    (__attribute__((address_space(3))) void*)(l), 16, 0, 0)

__device__ __forceinline__ unsigned short f2b(float f) {   // RNE
  union { float f; unsigned u; } c; c.f = f;
  unsigned r = c.u + 0x7fffu + ((c.u >> 16) & 1u);
  return (unsigned short)(r >> 16);
}

// round-to-nearest both floats, pack bf16(hi)<<16 | bf16(lo) in ONE v_perm
__device__ __forceinline__ unsigned pack2(float lo, float hi) {
  union { float f; unsigned u; } a, b; a.f = lo; b.f = hi;
  return __builtin_amdgcn_perm(b.u + 0x8000u, a.u + 0x8000u, 0x07060302u);
}

__device__ __forceinline__ float fast_tanh(float x) {
  float e = __expf(2.0f * x);
  return 1.0f - 2.0f / (e + 1.0f);
}

// We (fp32, W[:,1024:2048]) -> bf16 k-chunked layout Bw2[k>>3][n][k&7] in ws.
// Also zeroes scoresT. Grid 512x256, thread -> one (kc, n) pair (8 k-elems).
__global__ __launch_bounds__(256) void k_cvtB(
    const float* __restrict__ W, unsigned int* __restrict__ Bw2,
    float* __restrict__ scoresT) {
  const int idx = blockIdx.x * 256 + threadIdx.x;    // 0..131071
  const int kc = idx >> 10, n = idx & 1023;
  const float* src = W + (size_t)n * 2048 + 1024 + kc * 8;
  float4 f0 = *(const float4*)(src);
  float4 f1 = *(const float4*)(src + 4);
  uint4v u = {pack2(f0.x, f0.y), pack2(f0.z, f0.w),
              pack2(f1.x, f1.y), pack2(f1.z, f1.w)};
  *(uint4v*)(Bw2 + ((size_t)kc * 8192 + n * 8) / 2) = u;   // 16 B, coalesced
  if (idx < 65536) scoresT[idx] = 0.f;
}

// tpre[b][ko] = sum_j hidden[b][j]*W[ko][j] + bias[ko]
// thread = (b = g&31, ko = g>>5): W row broadcast across 32 lanes, read once.
__global__ __launch_bounds__(256) void k_preh(
    const float* __restrict__ hidden, const float* __restrict__ W,
    const float* __restrict__ bias, float* __restrict__ tpre) {
  const int g  = blockIdx.x * 256 + threadIdx.x;   // 0..32767
  const int b  = g & 31;
  const int ko = g >> 5;
  const float* wr = W + (size_t)ko * 2048;
  const float* hr = hidden + b * 1024;
  float s = 0.f;
  #pragma unroll 8
  for (int j = 0; j < 1024; j += 4) {
    float4 wv = *(const float4*)(wr + j);     // broadcast within half-wave
    float4 hv = *(const float4*)(hr + j);
    s += wv.x * hv.x + wv.y * hv.y + wv.z * hv.z + wv.w * hv.w;
  }
  tpre[b * 1024 + ko] = s + bias[ko];
}

// Fused GEMM + tanh + v-dot. Tile 64(m) x 128(n), BK=64, 4 waves (2x2 of 32x64).
// Single-buffer, 2 barriers/iter; TLP (4 blocks/CU) hides the HBM drain.
__global__ __launch_bounds__(256, 4) void k_gemm(
    const float* __restrict__ A,              // enc [65536][1024] fp32
    const unsigned short* __restrict__ Bw2,   // We bf16 [128 kc][1024 n][8]
    const float* __restrict__ tpre,           // [32][1024]
    const float* __restrict__ vvec,           // [1024]
    float* __restrict__ scoresT) {            // [32][2048], pre-zeroed
  __shared__ short As[64 * LDA];              // 9216 B
  __shared__ short Bs[8 * 128 * 8];           // [kc][n][8], 16384 B

  // XCD swizzle: the 8 n-blocks of one 64-row m-panel share blockIdx%8 -> one XCD
  const int l = blockIdx.x;
  const int x = l & 7, j = l >> 3;
  const int Mbase = (x * 128 + (j >> 3)) * 64;   // 1024 m-panels of 64 rows
  const int Nbase = (j & 7) * 128;

  const int tid = threadIdx.x, lane = tid & 63, w = tid >> 6;
  const int wm = w >> 1, wn = w & 1;
  const int c = lane & 15, q = lane >> 4;

  // A staging: thread -> row tid>>2, 16 consecutive k at (tid&3)*16
  const int arow = tid >> 2, acol = (tid & 3) << 4;
  const float* ap = A + (size_t)(Mbase + arow) * 1024 + acol;
  short* asw = &As[arow * LDA + acol];

  // B staging: 16 GLDS of 1 KB; seg = w*4+i -> kc_local = seg>>1, n-half = seg&1
  // global: Bw2[kc_g][Nbase + half*64 + lane][0..7]  (lane-contiguous 16 B)
  // lds   : Bs[kc_local][half*64 + lane][0..7]       (= base + lane*16)
  const unsigned short* bgb = Bw2 + (size_t)(Nbase + lane) * 8;

  floatx4 acc[2][4];
  #pragma unroll
  for (int mt = 0; mt < 2; ++mt)
    #pragma unroll
    for (int nt = 0; nt < 4; ++nt) {
      floatx4 z = {0.f, 0.f, 0.f, 0.f};
      acc[mt][nt] = z;
    }

  for (int k0 = 0; k0 < 1024; k0 += 64) {
    // ---- stage (A longest pole first, then B; all in flight together) ----
    float4 g0 = *(const float4*)(ap + k0);
    float4 g1 = *(const float4*)(ap + k0 + 4);
    float4 g2 = *(const float4*)(ap + k0 + 8);
    float4 g3 = *(const float4*)(ap + k0 + 12);
    #pragma unroll
    for (int i = 0; i < 4; ++i) {
      const int seg = w * 4 + i;
      const int kcl = seg >> 1, half = seg & 1;
      GLDS(bgb + ((size_t)((k0 >> 3) + kcl) * 8192 + half * 512),
           &Bs[kcl * 1024 + half * 512]);
    }
    uint4v u0 = {pack2(g0.x, g0.y), pack2(g0.z, g0.w),
                 pack2(g1.x, g1.y), pack2(g1.z, g1.w)};
    uint4v u1 = {pack2(g2.x, g2.y), pack2(g2.z, g2.w),
                 pack2(g3.x, g3.y), pack2(g3.z, g3.w)};
    *(uint4v*)asw = u0;
    *(uint4v*)(asw + 8) = u1;
    __syncthreads();                       // staging visible

    // ---- compute: 2 k-steps of 32, 8 MFMAs each ----
    #pragma unroll
    for (int ks = 0; ks < 2; ++ks) {
      short8 af[2], bf[4];
      #pragma unroll
      for (int mt = 0; mt < 2; ++mt)
        af[mt] = *(const short8*)&As[(wm * 32 + mt * 16 + c) * LDA + ks * 32 + q * 8];
      #pragma unroll
      for (int nt = 0; nt < 4; ++nt)
        bf[nt] = *(const short8*)&Bs[(ks * 4 + q) * 1024 + (wn * 64 + nt * 16 + c) * 8];
      #pragma unroll
      for (int mt = 0; mt < 2; ++mt)
        #pragma unroll
        for (int nt = 0; nt < 4; ++nt)
          acc[mt][nt] = __builtin_amdgcn_mfma_f32_16x16x32_bf16(
              af[mt], bf[nt], acc[mt][nt], 0, 0, 0);
    }
    __syncthreads();                       // frag reads done before next stage
  }

  // Epilogue: score[m] += sum_n tanh(pre_e + tpre[b][n]) * v[n]
  // C layout: col = lane&15, row = (lane>>4)*4 + i
  const int mwave = Mbase + wm * 32;
  const int nwave = Nbase + wn * 64;
  float vv[4];
  #pragma unroll
  for (int nt = 0; nt < 4; ++nt) vv[nt] = vvec[nwave + nt * 16 + c];
  #pragma unroll
  for (int mt = 0; mt < 2; ++mt) {
    #pragma unroll
    for (int i = 0; i < 4; ++i) {
      const int mrow = mwave + mt * 16 + q * 4 + i;
      const float* tb = tpre + (mrow & 31) * 1024;
      float ssum = 0.f;
      #pragma unroll
      for (int nt = 0; nt < 4; ++nt) {
        float pre = acc[mt][nt][i] + tb[nwave + nt * 16 + c];
        ssum += fast_tanh(pre) * vv[nt];
      }
      #pragma unroll
      for (int off = 1; off < 16; off <<= 1) ssum += __shfl_xor(ssum, off, 64);
      if (c == 0) atomicAdd(&scoresT[(mrow & 31) * 2048 + (mrow >> 5)], ssum);
    }
  }
}

// softmax over s for each b: scoresT[b][s] -> out[b][s]  (coalesced)
__global__ __launch_bounds__(256) void k_softmax(
    const float* __restrict__ scoresT, float* __restrict__ out) {
  const int b = blockIdx.x;
  const int t = threadIdx.x;
  const int w = t >> 6, lane = t & 63;
  __shared__ float red[4];
  float vals[8];
  float m = -3.0e38f;
  #pragma unroll
  for (int i = 0; i < 8; ++i) {
    vals[i] = scoresT[b * 2048 + t + 256 * i];
    m = fmaxf(m, vals[i]);
  }
  #pragma unroll
  for (int off = 32; off; off >>= 1) m = fmaxf(m, __shfl_xor(m, off, 64));
  if (lane == 0) red[w] = m;
  __syncthreads();
  m = fmaxf(fmaxf(red[0], red[1]), fmaxf(red[2], red[3]));
  __syncthreads();
  float e[8];
  float sum = 0.f;
  #pragma unroll
  for (int i = 0; i < 8; ++i) { e[i] = __expf(vals[i] - m); sum += e[i]; }
  #pragma unroll
  for (int off = 32; off; off >>= 1) sum += __shfl_xor(sum, off, 64);
  if (lane == 0) red[w] = sum;
  __syncthreads();
  sum = red[0] + red[1] + red[2] + red[3];
  const float inv = 1.0f / sum;
  #pragma unroll
  for (int i = 0; i < 8; ++i) out[b * 2048 + t + 256 * i] = e[i] * inv;
}

extern "C" void kernel_launch(void* const* d_in, const int* in_sizes, int n_in,
                              void* d_out, int out_size, void* d_ws, size_t ws_size,
                              hipStream_t stream) {
  const float* hidden = (const float*)d_in[0];   // (1,32,1024)
  const float* enc    = (const float*)d_in[1];   // (2048,32,1024)
  const float* W      = (const float*)d_in[2];   // (1024,2048)
  const float* bias   = (const float*)d_in[3];   // (1024,)
  const float* vvec   = (const float*)d_in[4];   // (1024,)
  float* out = (float*)d_out;                    // (32,1,2048) fp32

  float* scoresT = (float*)d_ws;                          // 65536 fp32
  float* tpre    = scoresT + 65536;                       // 32768 fp32
  unsigned int* Bw2 = (unsigned int*)(tpre + 32768);      // 1M bf16 = 2 MB

  hipLaunchKernelGGL(k_cvtB, dim3(512), dim3(256), 0, stream, W, Bw2, scoresT);
  hipLaunchKernelGGL(k_preh, dim3(128), dim3(256), 0, stream, hidden, W, bias, tpre);
  hipLaunchKernelGGL(k_gemm, dim3(8192), dim3(256), 0, stream,
                     enc, (const unsigned short*)Bw2, tpre, vvec, scoresT);
  hipLaunchKernelGGL(k_softmax, dim3(32), dim3(256), 0, stream, scoresT, out);
}